// Round 1
// baseline (1682.106 us; speedup 1.0000x reference)
//
#include <hip/hip_runtime.h>

#define S_LEN 2048
#define B_SZ  2
#define E_SZ  1024
#define H_SZ  16
#define D_SZ  64

// ---------------------------------------------------------------------------
// Generic pattern: 64x64 output tile, 256 threads (16x16), 4x4 per thread,
// K staged in LDS transposed as [k][row] with row-stride 68 (16B aligned).
// ---------------------------------------------------------------------------

// C[r,n] = sum_k X[r,k]*W[n,k] + bias[n], output scattered to Q/K/V [B,H,S,D]
__global__ __launch_bounds__(256) void proj_qkv_kernel(
    const float* __restrict__ X,    // [S*B, E] row r = s*B + b
    const float* __restrict__ W,    // [E, E]
    const float* __restrict__ bias, // [E]
    float* __restrict__ out)        // [B,H,S,D]
{
    __shared__ float sA[16][68];
    __shared__ float sW[16][68];
    const int tx = threadIdx.x, ty = threadIdx.y;
    const int t  = ty * 16 + tx;
    const int n0 = blockIdx.x * 64;
    const int m0 = blockIdx.y * 64;
    const int K  = E_SZ;

    const int r_loc = t >> 2;
    const int kq    = (t & 3) * 4;

    float acc[4][4] = {};

    for (int k0 = 0; k0 < K; k0 += 16) {
        float4 a = *(const float4*)&X[(size_t)(m0 + r_loc) * K + k0 + kq];
        float4 w = *(const float4*)&W[(size_t)(n0 + r_loc) * K + k0 + kq];
        sA[kq+0][r_loc] = a.x; sA[kq+1][r_loc] = a.y;
        sA[kq+2][r_loc] = a.z; sA[kq+3][r_loc] = a.w;
        sW[kq+0][r_loc] = w.x; sW[kq+1][r_loc] = w.y;
        sW[kq+2][r_loc] = w.z; sW[kq+3][r_loc] = w.w;
        __syncthreads();
        #pragma unroll
        for (int kk = 0; kk < 16; ++kk) {
            float4 av = *(const float4*)&sA[kk][ty * 4];
            float4 wv = *(const float4*)&sW[kk][tx * 4];
            float aa[4] = {av.x, av.y, av.z, av.w};
            float ww[4] = {wv.x, wv.y, wv.z, wv.w};
            #pragma unroll
            for (int i = 0; i < 4; ++i)
                #pragma unroll
                for (int j = 0; j < 4; ++j)
                    acc[i][j] += aa[i] * ww[j];
        }
        __syncthreads();
    }

    #pragma unroll
    for (int i = 0; i < 4; ++i) {
        int r = m0 + ty * 4 + i;
        int s = r >> 1;      // r = s*B + b, B = 2
        int b = r & 1;
        #pragma unroll
        for (int j = 0; j < 4; ++j) {
            int n = n0 + tx * 4 + j;
            int h = n >> 6, d = n & 63;
            out[(((size_t)(b * H_SZ + h) * S_LEN) + s) * D_SZ + d] = acc[i][j] + bias[n];
        }
    }
}

// out[s,b,n] = sum_e ctx[b,s,e]*Wo[n,e] + bo[n]
__global__ __launch_bounds__(256) void proj_out_kernel(
    const float* __restrict__ X,    // ctx [B*S, E] row r = b*S + s
    const float* __restrict__ W,    // [E, E]
    const float* __restrict__ bias, // [E]
    float* __restrict__ out)        // [S,B,E]
{
    __shared__ float sA[16][68];
    __shared__ float sW[16][68];
    const int tx = threadIdx.x, ty = threadIdx.y;
    const int t  = ty * 16 + tx;
    const int n0 = blockIdx.x * 64;
    const int m0 = blockIdx.y * 64;
    const int K  = E_SZ;

    const int r_loc = t >> 2;
    const int kq    = (t & 3) * 4;

    float acc[4][4] = {};

    for (int k0 = 0; k0 < K; k0 += 16) {
        float4 a = *(const float4*)&X[(size_t)(m0 + r_loc) * K + k0 + kq];
        float4 w = *(const float4*)&W[(size_t)(n0 + r_loc) * K + k0 + kq];
        sA[kq+0][r_loc] = a.x; sA[kq+1][r_loc] = a.y;
        sA[kq+2][r_loc] = a.z; sA[kq+3][r_loc] = a.w;
        sW[kq+0][r_loc] = w.x; sW[kq+1][r_loc] = w.y;
        sW[kq+2][r_loc] = w.z; sW[kq+3][r_loc] = w.w;
        __syncthreads();
        #pragma unroll
        for (int kk = 0; kk < 16; ++kk) {
            float4 av = *(const float4*)&sA[kk][ty * 4];
            float4 wv = *(const float4*)&sW[kk][tx * 4];
            float aa[4] = {av.x, av.y, av.z, av.w};
            float ww[4] = {wv.x, wv.y, wv.z, wv.w};
            #pragma unroll
            for (int i = 0; i < 4; ++i)
                #pragma unroll
                for (int j = 0; j < 4; ++j)
                    acc[i][j] += aa[i] * ww[j];
        }
        __syncthreads();
    }

    #pragma unroll
    for (int i = 0; i < 4; ++i) {
        int r = m0 + ty * 4 + i;
        int b = r >> 11;     // r = b*S + s, S = 2048
        int s = r & 2047;
        #pragma unroll
        for (int j = 0; j < 4; ++j) {
            int n = n0 + tx * 4 + j;
            out[((size_t)s * B_SZ + b) * E_SZ + n] = acc[i][j] + bias[n];
        }
    }
}

// scores[bh,q,k] = (Q[bh,q,:] . K[bh,k,:]) * 0.125 + biasM[q,k]
__global__ __launch_bounds__(256) void scores_kernel(
    const float* __restrict__ Q,     // [B*H, S, D]
    const float* __restrict__ Km,    // [B*H, S, D]
    const float* __restrict__ biasM, // [S, S]
    float* __restrict__ attn)        // [B*H, S, S] raw scores
{
    __shared__ float sQ[64][68];
    __shared__ float sK[64][68];
    const int tx = threadIdx.x, ty = threadIdx.y;
    const int t  = ty * 16 + tx;
    const int k0 = blockIdx.x * 64;
    const int q0 = blockIdx.y * 64;
    const int bh = blockIdx.z;
    const float* Qb = Q  + (size_t)bh * S_LEN * D_SZ;
    const float* Kb = Km + (size_t)bh * S_LEN * D_SZ;

    #pragma unroll
    for (int rep = 0; rep < 4; ++rep) {
        int idx = t + rep * 256;
        int row = idx >> 4;
        int dq  = (idx & 15) * 4;
        float4 q4 = *(const float4*)&Qb[(size_t)(q0 + row) * D_SZ + dq];
        float4 k4 = *(const float4*)&Kb[(size_t)(k0 + row) * D_SZ + dq];
        sQ[dq+0][row] = q4.x; sQ[dq+1][row] = q4.y;
        sQ[dq+2][row] = q4.z; sQ[dq+3][row] = q4.w;
        sK[dq+0][row] = k4.x; sK[dq+1][row] = k4.y;
        sK[dq+2][row] = k4.z; sK[dq+3][row] = k4.w;
    }
    __syncthreads();

    float acc[4][4] = {};
    #pragma unroll 16
    for (int d = 0; d < 64; ++d) {
        float4 qv = *(const float4*)&sQ[d][ty * 4];
        float4 kv = *(const float4*)&sK[d][tx * 4];
        float qq[4] = {qv.x, qv.y, qv.z, qv.w};
        float kk[4] = {kv.x, kv.y, kv.z, kv.w};
        #pragma unroll
        for (int i = 0; i < 4; ++i)
            #pragma unroll
            for (int j = 0; j < 4; ++j)
                acc[i][j] += qq[i] * kk[j];
    }

    const float scale = 0.125f;  // D^-0.5
    #pragma unroll
    for (int i = 0; i < 4; ++i) {
        int q = q0 + ty * 4 + i;
        #pragma unroll
        for (int j = 0; j < 4; ++j) {
            int kc = k0 + tx * 4 + j;
            attn[((size_t)bh * S_LEN + q) * S_LEN + kc] =
                acc[i][j] * scale + biasM[(size_t)q * S_LEN + kc];
        }
    }
}

// in-place row softmax over last dim (2048), one block per row
__global__ __launch_bounds__(256) void softmax_kernel(float* __restrict__ attn)
{
    const size_t row = blockIdx.x;
    float* p = attn + row * S_LEN;
    const int t = threadIdx.x;

    float4 v0 = *(const float4*)&p[t * 4];
    float4 v1 = *(const float4*)&p[1024 + t * 4];
    float v[8] = {v0.x, v0.y, v0.z, v0.w, v1.x, v1.y, v1.z, v1.w};

    float m = v[0];
    #pragma unroll
    for (int i = 1; i < 8; ++i) m = fmaxf(m, v[i]);
    #pragma unroll
    for (int off = 32; off; off >>= 1) m = fmaxf(m, __shfl_xor(m, off, 64));

    __shared__ float redm[4];
    __shared__ float reds[4];
    const int wave = t >> 6, lane = t & 63;
    if (lane == 0) redm[wave] = m;
    __syncthreads();
    m = fmaxf(fmaxf(redm[0], redm[1]), fmaxf(redm[2], redm[3]));

    float sum = 0.f;
    #pragma unroll
    for (int i = 0; i < 8; ++i) { v[i] = __expf(v[i] - m); sum += v[i]; }
    #pragma unroll
    for (int off = 32; off; off >>= 1) sum += __shfl_xor(sum, off, 64);
    if (lane == 0) reds[wave] = sum;
    __syncthreads();
    sum = reds[0] + reds[1] + reds[2] + reds[3];

    const float inv = 1.0f / sum;
    float4 o0 = make_float4(v[0]*inv, v[1]*inv, v[2]*inv, v[3]*inv);
    float4 o1 = make_float4(v[4]*inv, v[5]*inv, v[6]*inv, v[7]*inv);
    *(float4*)&p[t * 4]        = o0;
    *(float4*)&p[1024 + t * 4] = o1;
}

// ctx[b,q,h*64+d] = sum_k attn[bh,q,k] * V[bh,k,d]
__global__ __launch_bounds__(256) void context_kernel(
    const float* __restrict__ P,  // [B*H, S, S] normalized attn
    const float* __restrict__ V,  // [B*H, S, D]
    float* __restrict__ ctx)      // [B, S, E]
{
    __shared__ float sP[16][68];
    __shared__ float sV[16][68];
    const int tx = threadIdx.x, ty = threadIdx.y;
    const int t  = ty * 16 + tx;
    const int q0 = blockIdx.x * 64;
    const int bh = blockIdx.y;
    const int b  = bh >> 4, h = bh & 15;
    const float* Pb = P + (size_t)bh * S_LEN * S_LEN;
    const float* Vb = V + (size_t)bh * S_LEN * D_SZ;

    const int q_loc = t >> 2;
    const int kq    = (t & 3) * 4;
    const int vk    = t >> 4;
    const int vd    = (t & 15) * 4;

    float acc[4][4] = {};

    for (int k0 = 0; k0 < S_LEN; k0 += 16) {
        float4 pp = *(const float4*)&Pb[(size_t)(q0 + q_loc) * S_LEN + k0 + kq];
        sP[kq+0][q_loc] = pp.x; sP[kq+1][q_loc] = pp.y;
        sP[kq+2][q_loc] = pp.z; sP[kq+3][q_loc] = pp.w;
        float4 vv4 = *(const float4*)&Vb[(size_t)(k0 + vk) * D_SZ + vd];
        *(float4*)&sV[vk][vd] = vv4;
        __syncthreads();
        #pragma unroll
        for (int kk = 0; kk < 16; ++kk) {
            float4 pv = *(const float4*)&sP[kk][ty * 4];
            float4 vv = *(const float4*)&sV[kk][tx * 4];
            float pa[4] = {pv.x, pv.y, pv.z, pv.w};
            float va[4] = {vv.x, vv.y, vv.z, vv.w};
            #pragma unroll
            for (int i = 0; i < 4; ++i)
                #pragma unroll
                for (int j = 0; j < 4; ++j)
                    acc[i][j] += pa[i] * va[j];
        }
        __syncthreads();
    }

    #pragma unroll
    for (int i = 0; i < 4; ++i) {
        int q = q0 + ty * 4 + i;
        #pragma unroll
        for (int j = 0; j < 4; ++j) {
            int d = tx * 4 + j;
            ctx[((size_t)b * S_LEN + q) * E_SZ + h * D_SZ + d] = acc[i][j];
        }
    }
}

extern "C" void kernel_launch(void* const* d_in, const int* in_sizes, int n_in,
                              void* d_out, int out_size, void* d_ws, size_t ws_size,
                              hipStream_t stream)
{
    const float* query = (const float*)d_in[0];
    const float* key_  = (const float*)d_in[1];
    const float* value = (const float*)d_in[2];
    const float* Wq    = (const float*)d_in[3];
    const float* bq    = (const float*)d_in[4];
    const float* Wk    = (const float*)d_in[5];
    const float* bk    = (const float*)d_in[6];
    const float* Wv    = (const float*)d_in[7];
    const float* bv    = (const float*)d_in[8];
    const float* Wo    = (const float*)d_in[9];
    const float* bo    = (const float*)d_in[10];
    const float* biasM = (const float*)d_in[11];

    float* out  = (float*)d_out;                                  // [S,B,E]
    float* attn = (float*)d_out + (size_t)S_LEN * B_SZ * E_SZ;    // [B,H,S,S]

    float* ws = (float*)d_ws;
    const size_t qsz = (size_t)B_SZ * H_SZ * S_LEN * D_SZ;        // 4M floats
    float* Q   = ws;
    float* K   = ws + qsz;
    float* V   = ws + 2 * qsz;
    float* ctx = ws + 3 * qsz;   // [B,S,E], 4M floats; total ws use = 64 MB

    dim3 blk(16, 16);
    dim3 gproj(E_SZ / 64, (S_LEN * B_SZ) / 64);
    proj_qkv_kernel<<<gproj, blk, 0, stream>>>(query, Wq, bq, Q);
    proj_qkv_kernel<<<gproj, blk, 0, stream>>>(key_,  Wk, bk, K);
    proj_qkv_kernel<<<gproj, blk, 0, stream>>>(value, Wv, bv, V);

    dim3 gsc(S_LEN / 64, S_LEN / 64, B_SZ * H_SZ);
    scores_kernel<<<gsc, blk, 0, stream>>>(Q, K, biasM, attn);

    softmax_kernel<<<dim3(B_SZ * H_SZ * S_LEN), dim3(256), 0, stream>>>(attn);

    dim3 gctx(S_LEN / 64, B_SZ * H_SZ);
    context_kernel<<<gctx, blk, 0, stream>>>(attn, V, ctx);

    proj_out_kernel<<<gproj, blk, 0, stream>>>(ctx, Wo, bo, out);
}